// Round 3
// baseline (1191.982 us; speedup 1.0000x reference)
//
#include <hip/hip_runtime.h>
#include <hip/hip_bf16.h>

#define BB 4
#define CPG 48
#define HH 128
#define WW2 128
#define PP 16384
#define DIM 384
#define DIM3 1152

typedef unsigned short u16;

__device__ __forceinline__ float bf2f(u16 u) {
    return __uint_as_float(((unsigned int)u) << 16);
}
__device__ __forceinline__ u16 f2bf(float f) {
    unsigned int u = __float_as_uint(f);
    unsigned int r = (u + 0x7fffu + ((u >> 16) & 1u)) >> 16;
    return (u16)r;
}

// ---------------- Kernel 1: 1x1 conv (GEMM 1152x384 @ 384x16384) -> bf16 y1
__global__ __launch_bounds__(256) void k_qkv(const float* __restrict__ x,
                                             const float* __restrict__ w,
                                             const float* __restrict__ bias,
                                             u16* __restrict__ y1)
{
    const int b   = blockIdx.z;
    const int co0 = blockIdx.y * 64;
    const int p0  = blockIdx.x * 64;
    const int t   = threadIdx.x;
    const int tx  = t & 15;
    const int ty  = t >> 4;

    __shared__ __align__(16) float Xs[16][64];
    __shared__ __align__(16) float Ws[16][64];

    float acc[4][4];
#pragma unroll
    for (int i = 0; i < 4; ++i)
#pragma unroll
        for (int j = 0; j < 4; ++j) acc[i][j] = 0.f;

    const float* xb = x + (size_t)b * DIM * PP;
    const int lkk = t >> 4;          // 0..15  (X tile row)
    const int lpx = (t & 15) * 4;    // X tile col*4
    const int wco = t >> 2;          // 0..63  (W tile col)
    const int wkc = (t & 3) * 4;     // W tile row*4

    for (int k0 = 0; k0 < DIM; k0 += 16) {
        float4 xv = *reinterpret_cast<const float4*>(&xb[(size_t)(k0 + lkk) * PP + p0 + lpx]);
        *reinterpret_cast<float4*>(&Xs[lkk][lpx]) = xv;
        float4 wv = *reinterpret_cast<const float4*>(&w[(size_t)(co0 + wco) * DIM + k0 + wkc]);
        Ws[wkc + 0][wco] = wv.x;
        Ws[wkc + 1][wco] = wv.y;
        Ws[wkc + 2][wco] = wv.z;
        Ws[wkc + 3][wco] = wv.w;
        __syncthreads();
#pragma unroll
        for (int kk = 0; kk < 16; ++kk) {
            float4 xr = *reinterpret_cast<const float4*>(&Xs[kk][tx * 4]);
            float4 wr = *reinterpret_cast<const float4*>(&Ws[kk][ty * 4]);
            float xa[4] = {xr.x, xr.y, xr.z, xr.w};
            float wa[4] = {wr.x, wr.y, wr.z, wr.w};
#pragma unroll
            for (int i = 0; i < 4; ++i)
#pragma unroll
                for (int j = 0; j < 4; ++j)
                    acc[i][j] = fmaf(wa[i], xa[j], acc[i][j]);
        }
        __syncthreads();
    }
#pragma unroll
    for (int i = 0; i < 4; ++i) {
        const int co = co0 + ty * 4 + i;
        const float bv = bias[co];
        ushort4 st;
        st.x = f2bf(acc[i][0] + bv);
        st.y = f2bf(acc[i][1] + bv);
        st.z = f2bf(acc[i][2] + bv);
        st.w = f2bf(acc[i][3] + bv);
        *reinterpret_cast<ushort4*>(&y1[((size_t)b * DIM3 + co) * PP + p0 + tx * 4]) = st;
    }
}

// ---------------- Kernel 2: depthwise 3x3 + bias -> bf16 y2
__global__ __launch_bounds__(256) void k_dw(const u16* __restrict__ y1,
                                            const float* __restrict__ wdw,
                                            const float* __restrict__ bdw,
                                            u16* __restrict__ y2)
{
    const int b  = blockIdx.z;
    const int ch = blockIdx.y;
    const int p  = (blockIdx.x * 256 + (int)threadIdx.x) * 8;
    const int row = p >> 7;
    const int col = p & 127;
    const size_t ib = ((size_t)b * DIM3 + ch) * PP;
    const u16* img = y1 + ib;

    float w9[9];
#pragma unroll
    for (int i = 0; i < 9; ++i) w9[i] = wdw[ch * 9 + i];
    const float bv = bdw[ch];

    float vr[3][10];
#pragma unroll
    for (int dy = 0; dy < 3; ++dy) {
        const int r = row + dy - 1;
        if (r >= 0 && r < HH) {
            const u16* rp = img + r * WW2 + col;
            union { int4 v; u16 u[8]; } cc;
            cc.v = *reinterpret_cast<const int4*>(rp);
#pragma unroll
            for (int j = 0; j < 8; ++j) vr[dy][j + 1] = bf2f(cc.u[j]);
            vr[dy][0] = (col > 0) ? bf2f(rp[-1]) : 0.f;
            vr[dy][9] = (col + 8 < WW2) ? bf2f(rp[8]) : 0.f;
        } else {
#pragma unroll
            for (int j = 0; j < 10; ++j) vr[dy][j] = 0.f;
        }
    }
    union { int4 v; u16 u[8]; } ou;
#pragma unroll
    for (int j = 0; j < 8; ++j) {
        float a = bv;
#pragma unroll
        for (int dy = 0; dy < 3; ++dy)
#pragma unroll
            for (int dx = 0; dx < 3; ++dx)
                a = fmaf(w9[dy * 3 + dx], vr[dy][j + dx], a);
        ou.u[j] = f2bf(a);
    }
    *reinterpret_cast<int4*>(y2 + ib + p) = ou.v;
}

// ---------------- Kernel 3: Gram-matrix partials (q.k, q.q, k.k) per batch
__global__ __launch_bounds__(256) void k_dots(const u16* __restrict__ y2,
                                              float* __restrict__ partial)
{
    const int b  = blockIdx.z;
    const int cy = blockIdx.y;      // 0..1 -> c halves
    const int c0 = cy * 24;
    const int p2 = (blockIdx.x * 256 + (int)threadIdx.x) * 2;
    const u16* qb = y2 + (size_t)b * DIM3 * PP + p2;
    const u16* kb = qb + (size_t)DIM * PP;

    float qk[64], qq[8], ks[8];
#pragma unroll
    for (int i = 0; i < 64; ++i) qk[i] = 0.f;
#pragma unroll
    for (int i = 0; i < 8; ++i) { qq[i] = 0.f; ks[i] = 0.f; }

    for (int c = c0; c < c0 + 24; ++c) {
        float q0[8], q1[8], k0[8], k1[8];
#pragma unroll
        for (int n = 0; n < 8; ++n) {
            const unsigned int qv = *reinterpret_cast<const unsigned int*>(qb + (size_t)(n * CPG + c) * PP);
            q0[n] = __uint_as_float(qv << 16);
            q1[n] = __uint_as_float(qv & 0xffff0000u);
            const unsigned int kv = *reinterpret_cast<const unsigned int*>(kb + (size_t)(n * CPG + c) * PP);
            k0[n] = __uint_as_float(kv << 16);
            k1[n] = __uint_as_float(kv & 0xffff0000u);
        }
#pragma unroll
        for (int n = 0; n < 8; ++n) {
#pragma unroll
            for (int m = 0; m < 8; ++m)
                qk[n * 8 + m] += q0[n] * k0[m] + q1[n] * k1[m];
            qq[n] += q0[n] * q0[n] + q1[n] * q1[n];
            ks[n] += k0[n] * k0[n] + k1[n] * k1[n];
        }
    }
    const int wave = (int)threadIdx.x >> 6;
    const int lane = (int)threadIdx.x & 63;
    const size_t rowidx = (size_t)((((b * 2 + cy) * 32 + blockIdx.x) * 4 + wave)) * 80;
#pragma unroll
    for (int i = 0; i < 80; ++i) {
        float v = (i < 64) ? qk[i] : ((i < 72) ? qq[i - 64] : ks[i - 72]);
        v += __shfl_down(v, 32);
        v += __shfl_down(v, 16);
        v += __shfl_down(v, 8);
        v += __shfl_down(v, 4);
        v += __shfl_down(v, 2);
        v += __shfl_down(v, 1);
        if (lane == 0) partial[rowidx + i] = v;
    }
}

// ---------------- Kernel 4: reduce partials, normalize, softmax -> attn[b][8][8]
__global__ __launch_bounds__(128) void k_attn(const float* __restrict__ partial,
                                              const float* __restrict__ temp,
                                              float* __restrict__ attn)
{
    const int b = blockIdx.x;
    const int t = threadIdx.x;
    __shared__ float dots[80];
    __shared__ float sc[8][8];
    if (t < 80) {
        float s = 0.f;
        for (int i = 0; i < 256; ++i)
            s += partial[((size_t)b * 256 + i) * 80 + t];
        dots[t] = s;
    }
    __syncthreads();
    if (t < 64) {
        const int n = t >> 3, m = t & 7;
        const float qn = fmaxf(sqrtf(dots[64 + n]), 1e-12f);
        const float km = fmaxf(sqrtf(dots[72 + m]), 1e-12f);
        sc[n][m] = dots[n * 8 + m] / (qn * km) * temp[0];
    }
    __syncthreads();
    if (t < 8) {
        float mx = -3.0e38f;
#pragma unroll
        for (int m = 0; m < 8; ++m) mx = fmaxf(mx, sc[t][m]);
        float e[8], s = 0.f;
#pragma unroll
        for (int m = 0; m < 8; ++m) { e[m] = expf(sc[t][m] - mx); s += e[m]; }
        const float inv = 1.f / s;
#pragma unroll
        for (int m = 0; m < 8; ++m) attn[(b * 8 + t) * 8 + m] = e[m] * inv;
    }
}

// ---------------- Kernel 5: Weff[b][co][m*48+c] = sum_n wproj[co][n*48+c]*attn[n][m]
__global__ __launch_bounds__(128) void k_weff(const float* __restrict__ attn,
                                              const float* __restrict__ wproj,
                                              float* __restrict__ weff)
{
    const int b  = blockIdx.y;
    const int co = blockIdx.x;
    const int t  = threadIdx.x;
    __shared__ float a[64];
    if (t < 64) a[t] = attn[b * 64 + t];
    __syncthreads();
    const float* wrow = wproj + (size_t)co * DIM;
    float* wout = weff + ((size_t)b * DIM + co) * DIM;
    for (int i = t; i < DIM; i += 128) {
        const int m = i / CPG;
        const int c = i - m * CPG;
        float s = 0.f;
#pragma unroll
        for (int n = 0; n < 8; ++n) s += wrow[n * CPG + c] * a[n * 8 + m];
        wout[i] = s;
    }
}

// ---------------- Kernel 6: out = Weff_b @ v + b_proj + x (GEMM 384x384 @ 384x16384)
__global__ __launch_bounds__(256) void k_out(const u16* __restrict__ y2,
                                             const float* __restrict__ weff,
                                             const float* __restrict__ bproj,
                                             const float* __restrict__ x,
                                             float* __restrict__ out)
{
    const int b   = blockIdx.z;
    const int co0 = blockIdx.y * 64;
    const int p0  = blockIdx.x * 64;
    const int t   = threadIdx.x;
    const int tx  = t & 15;
    const int ty  = t >> 4;

    __shared__ __align__(16) float Vs[16][64];
    __shared__ __align__(16) float Ws[16][64];

    float acc[4][4];
#pragma unroll
    for (int i = 0; i < 4; ++i)
#pragma unroll
        for (int j = 0; j < 4; ++j) acc[i][j] = 0.f;

    const u16* vb = y2 + ((size_t)b * DIM3 + 2 * DIM) * PP;
    const float* wb = weff + (size_t)b * DIM * DIM;
    const int lkk = t >> 4;
    const int lpx = (t & 15) * 4;
    const int wco = t >> 2;
    const int wkc = (t & 3) * 4;

    for (int k0 = 0; k0 < DIM; k0 += 16) {
        ushort4 vv = *reinterpret_cast<const ushort4*>(&vb[(size_t)(k0 + lkk) * PP + p0 + lpx]);
        Vs[lkk][lpx + 0] = bf2f(vv.x);
        Vs[lkk][lpx + 1] = bf2f(vv.y);
        Vs[lkk][lpx + 2] = bf2f(vv.z);
        Vs[lkk][lpx + 3] = bf2f(vv.w);
        float4 wv = *reinterpret_cast<const float4*>(&wb[(size_t)(co0 + wco) * DIM + k0 + wkc]);
        Ws[wkc + 0][wco] = wv.x;
        Ws[wkc + 1][wco] = wv.y;
        Ws[wkc + 2][wco] = wv.z;
        Ws[wkc + 3][wco] = wv.w;
        __syncthreads();
#pragma unroll
        for (int kk = 0; kk < 16; ++kk) {
            float4 xr = *reinterpret_cast<const float4*>(&Vs[kk][tx * 4]);
            float4 wr = *reinterpret_cast<const float4*>(&Ws[kk][ty * 4]);
            float xa[4] = {xr.x, xr.y, xr.z, xr.w};
            float wa[4] = {wr.x, wr.y, wr.z, wr.w};
#pragma unroll
            for (int i = 0; i < 4; ++i)
#pragma unroll
                for (int j = 0; j < 4; ++j)
                    acc[i][j] = fmaf(wa[i], xa[j], acc[i][j]);
        }
        __syncthreads();
    }
#pragma unroll
    for (int i = 0; i < 4; ++i) {
        const int co = co0 + ty * 4 + i;
        const float bv = bproj[co];
        const size_t idx = ((size_t)b * DIM + co) * PP + p0 + tx * 4;
        float4 xr = *reinterpret_cast<const float4*>(&x[idx]);
        float4 st;
        st.x = acc[i][0] + bv + xr.x;
        st.y = acc[i][1] + bv + xr.y;
        st.z = acc[i][2] + bv + xr.z;
        st.w = acc[i][3] + bv + xr.w;
        *reinterpret_cast<float4*>(&out[idx]) = st;
    }
}

extern "C" void kernel_launch(void* const* d_in, const int* in_sizes, int n_in,
                              void* d_out, int out_size, void* d_ws, size_t ws_size,
                              hipStream_t stream)
{
    const float* x      = (const float*)d_in[0];
    const float* temp   = (const float*)d_in[1];
    const float* w_qkv  = (const float*)d_in[2];
    const float* b_qkv  = (const float*)d_in[3];
    const float* w_dw   = (const float*)d_in[4];
    const float* b_dw   = (const float*)d_in[5];
    const float* w_proj = (const float*)d_in[6];
    const float* b_proj = (const float*)d_in[7];
    float* out = (float*)d_out;

    char* ws = (char*)d_ws;
    const size_t SZ_QKV = (size_t)BB * DIM3 * PP * sizeof(u16); // 150,994,944 B
    u16* y1 = (u16*)ws;
    u16* y2 = (u16*)(ws + SZ_QKV);
    // partial/attn/weff alias the y1 region (y1 is dead after k_dw)
    float* partial = (float*)ws;                               // 4*256*80*4 = 327,680 B
    float* attn    = (float*)(ws + 327680);                    // 1,024 B
    float* weff    = (float*)(ws + 331776);                    // 2,359,296 B

    k_qkv <<<dim3(PP / 64, DIM3 / 64, BB), 256, 0, stream>>>(x, w_qkv, b_qkv, y1);
    k_dw  <<<dim3(PP / 2048, DIM3, BB),    256, 0, stream>>>(y1, w_dw, b_dw, y2);
    k_dots<<<dim3(32, 2, BB),              256, 0, stream>>>(y2, partial);
    k_attn<<<dim3(BB),                     128, 0, stream>>>(partial, temp, attn);
    k_weff<<<dim3(DIM, BB),                128, 0, stream>>>(attn, w_proj, weff);
    k_out <<<dim3(PP / 64, DIM / 64, BB),  256, 0, stream>>>(y2, weff, b_proj, x, out);
}

// Round 6
// 741.235 us; speedup vs baseline: 1.6081x; 1.6081x over previous
//
#include <hip/hip_runtime.h>
#include <hip/hip_bf16.h>

#define BB 4
#define CPG 48
#define HH 128
#define WW2 128
#define PP 16384
#define DIM 384
#define DIM3 1152

typedef unsigned short u16;
typedef __attribute__((ext_vector_type(8))) short bf16x8;
typedef __attribute__((ext_vector_type(4))) float f32x4;

__device__ __forceinline__ float bf2f(u16 u) {
    return __uint_as_float(((unsigned int)u) << 16);
}
__device__ __forceinline__ u16 f2bf(float f) {
    unsigned int u = __float_as_uint(f);
    unsigned int r = (u + 0x7fffu + ((u >> 16) & 1u)) >> 16;
    return (u16)r;
}

// LDS swizzle: rows are 128B; XOR the 16B-slot index with (row&7) to spread banks
__device__ __forceinline__ int swz(int row, int kb) {
    return row * 128 + (kb ^ ((row & 7) << 4));
}

// ---------------- convert w_qkv fp32 -> bf16
__global__ __launch_bounds__(256) void k_wcvt(const float* __restrict__ w,
                                              u16* __restrict__ wbf)
{
    const int i4 = (blockIdx.x * 256 + threadIdx.x) * 4;
    float4 v = *reinterpret_cast<const float4*>(w + i4);
    ushort4 s;
    s.x = f2bf(v.x); s.y = f2bf(v.y); s.z = f2bf(v.z); s.w = f2bf(v.w);
    *reinterpret_cast<ushort4*>(wbf + i4) = s;
}

// ---------------- transpose x [b][k=384][p] fp32 -> Xt [b][p][k=384] bf16
__global__ __launch_bounds__(256) void k_tr_x(const float* __restrict__ x,
                                              u16* __restrict__ xt)
{
    const int b = blockIdx.z;
    const int k0 = blockIdx.y * 64;
    const int p0 = blockIdx.x * 64;
    const int t = threadIdx.x;
    __shared__ u16 T[64][68];

    const int kl = t >> 4;          // 0..15
    const int pl = (t & 15) * 4;    // 0..60
#pragma unroll
    for (int ks = 0; ks < 4; ++ks) {
        const int k = ks * 16 + kl;
        float4 v = *reinterpret_cast<const float4*>(&x[((size_t)b * DIM + k0 + k) * PP + p0 + pl]);
        ushort4 s;
        s.x = f2bf(v.x); s.y = f2bf(v.y); s.z = f2bf(v.z); s.w = f2bf(v.w);
        *reinterpret_cast<ushort4*>(&T[k][pl]) = s;
    }
    __syncthreads();
    const int pr = t >> 2;          // 0..63
    const int kg = (t & 3) * 16;    // 0,16,32,48
    __align__(16) u16 tmp[16];
#pragma unroll
    for (int j = 0; j < 16; ++j) tmp[j] = T[kg + j][pr];
    u16* dst = xt + ((size_t)b * PP + p0 + pr) * DIM + k0 + kg;
    *reinterpret_cast<uint4*>(dst)     = *reinterpret_cast<uint4*>(tmp);
    *reinterpret_cast<uint4*>(dst + 8) = *reinterpret_cast<uint4*>(tmp + 8);
}

// ---------------- transpose v part of y2 [b][768+c][p] bf16 -> Vt [b][p][c=384] bf16
__global__ __launch_bounds__(256) void k_tr_v(const u16* __restrict__ y2,
                                              u16* __restrict__ vt)
{
    const int b = blockIdx.z;
    const int c0 = blockIdx.y * 64;
    const int p0 = blockIdx.x * 64;
    const int t = threadIdx.x;
    __shared__ u16 T[64][68];

    const int cl = t >> 4;
    const int pl = (t & 15) * 4;
#pragma unroll
    for (int cs = 0; cs < 4; ++cs) {
        const int c = cs * 16 + cl;
        ushort4 v = *reinterpret_cast<const ushort4*>(
            &y2[((size_t)b * DIM3 + 2 * DIM + c0 + c) * PP + p0 + pl]);
        *reinterpret_cast<ushort4*>(&T[c][pl]) = v;
    }
    __syncthreads();
    const int pr = t >> 2;
    const int kg = (t & 3) * 16;
    __align__(16) u16 tmp[16];
#pragma unroll
    for (int j = 0; j < 16; ++j) tmp[j] = T[kg + j][pr];
    u16* dst = vt + ((size_t)b * PP + p0 + pr) * DIM + c0 + kg;
    *reinterpret_cast<uint4*>(dst)     = *reinterpret_cast<uint4*>(tmp);
    *reinterpret_cast<uint4*>(dst + 8) = *reinterpret_cast<uint4*>(tmp + 8);
}

// ---------------- MFMA GEMM: C[b][co][p] = sum_k A[(b)][co][k] * Bt[b][p][k]
// MODE 0: += bias, write bf16 ybf.  MODE 1: += bias + xres, write fp32 fout.
template<int MODE>
__global__ __launch_bounds__(256) void k_gemm(const u16* __restrict__ A, int aStride,
                                              const u16* __restrict__ Bt,
                                              const float* __restrict__ bias,
                                              u16* __restrict__ ybf,
                                              const float* __restrict__ xres,
                                              float* __restrict__ fout)
{
    const int b   = blockIdx.z;
    const int co0 = blockIdx.y * 128;
    const int p0  = blockIdx.x * 128;
    const int t   = threadIdx.x;
    const int l   = t & 63;
    const int wid = t >> 6;
    const int wr  = wid >> 1;      // 0..1 -> row half
    const int wc  = wid & 1;       // 0..1 -> col half
    const int lr  = l & 15;
    const int lg  = l >> 4;        // 0..3

    __shared__ __align__(16) char lds[32768];
    char* AsB = lds;               // [128 rows][64 k] bf16, swizzled
    char* BsB = lds + 16384;

    f32x4 acc[4][4];
#pragma unroll
    for (int m = 0; m < 4; ++m)
#pragma unroll
        for (int n = 0; n < 4; ++n) acc[m][n] = (f32x4){0.f, 0.f, 0.f, 0.f};

    const u16* Ab  = A  + (size_t)b * aStride;
    const u16* Btb = Bt + (size_t)b * PP * DIM;

    const int srow = t >> 1;       // 0..127
    const int shalf = t & 1;       // 0..1 (32 bf16 = 64B)

    for (int k0 = 0; k0 < DIM; k0 += 64) {
        const u16* sa = Ab  + (size_t)(co0 + srow) * DIM + k0 + shalf * 32;
        const u16* sb = Btb + (size_t)(p0  + srow) * DIM + k0 + shalf * 32;
        uint4 ra[2], rb[2];
#pragma unroll
        for (int i = 0; i < 2; ++i) {
            ra[i] = *reinterpret_cast<const uint4*>(sa + i * 8);
            rb[i] = *reinterpret_cast<const uint4*>(sb + i * 8);
        }
        uint4 ra2[2], rb2[2];
#pragma unroll
        for (int i = 0; i < 2; ++i) {
            ra2[i] = *reinterpret_cast<const uint4*>(sa + 16 + i * 8);
            rb2[i] = *reinterpret_cast<const uint4*>(sb + 16 + i * 8);
        }
        if (k0) __syncthreads();
#pragma unroll
        for (int i = 0; i < 2; ++i) {
            const int kb = shalf * 64 + i * 16;
            *reinterpret_cast<uint4*>(AsB + swz(srow, kb)) = ra[i];
            *reinterpret_cast<uint4*>(BsB + swz(srow, kb)) = rb[i];
        }
#pragma unroll
        for (int i = 0; i < 2; ++i) {
            const int kb = shalf * 64 + 32 + i * 16;
            *reinterpret_cast<uint4*>(AsB + swz(srow, kb)) = ra2[i];
            *reinterpret_cast<uint4*>(BsB + swz(srow, kb)) = rb2[i];
        }
        __syncthreads();

#pragma unroll
        for (int kk = 0; kk < 64; kk += 32) {
            const int kbyte = kk * 2 + lg * 16;
            bf16x8 av[4], bv[4];
#pragma unroll
            for (int m = 0; m < 4; ++m) {
                const int row = wr * 64 + m * 16 + lr;
                av[m] = *reinterpret_cast<const bf16x8*>(AsB + swz(row, kbyte));
            }
#pragma unroll
            for (int n = 0; n < 4; ++n) {
                const int row = wc * 64 + n * 16 + lr;
                bv[n] = *reinterpret_cast<const bf16x8*>(BsB + swz(row, kbyte));
            }
#pragma unroll
            for (int m = 0; m < 4; ++m)
#pragma unroll
                for (int n = 0; n < 4; ++n)
                    acc[m][n] = __builtin_amdgcn_mfma_f32_16x16x32_bf16(
                        av[m], bv[n], acc[m][n], 0, 0, 0);
        }
    }

    // bias per (m, r): row = wr*64 + m*16 + lg*4 + r
    float bias_r[4][4];
#pragma unroll
    for (int m = 0; m < 4; ++m)
#pragma unroll
        for (int r = 0; r < 4; ++r)
            bias_r[m][r] = bias[co0 + wr * 64 + m * 16 + lg * 4 + r];

    if (MODE == 0) {
        __syncthreads();
        u16* Cs = reinterpret_cast<u16*>(lds);
#pragma unroll
        for (int m = 0; m < 4; ++m)
#pragma unroll
            for (int n = 0; n < 4; ++n)
#pragma unroll
                for (int r = 0; r < 4; ++r) {
                    const int row = wr * 64 + m * 16 + lg * 4 + r;
                    const int col = wc * 64 + n * 16 + lr;
                    Cs[row * 128 + col] = f2bf(acc[m][n][r] + bias_r[m][r]);
                }
        __syncthreads();
        // full-tile store: each thread copies 64 u16 (128 rows x 128 cols total)
        const int row = t >> 1;
        const int half = t & 1;
        const char* src = lds + row * 256 + half * 128;
        u16* dst = ybf + ((size_t)b * DIM3 + co0 + row) * PP + p0 + half * 64;
#pragma unroll
        for (int i = 0; i < 8; ++i)
            *reinterpret_cast<uint4*>(dst + i * 8) =
                *reinterpret_cast<const uint4*>(src + i * 16);
    } else {
#pragma unroll
        for (int m = 0; m < 4; ++m)
#pragma unroll
            for (int n = 0; n < 4; ++n)
#pragma unroll
                for (int r = 0; r < 4; ++r) {
                    const int row = wr * 64 + m * 16 + lg * 4 + r;
                    const int col = wc * 64 + n * 16 + lr;
                    const size_t idx = ((size_t)b * DIM + co0 + row) * PP + p0 + col;
                    fout[idx] = acc[m][n][r] + bias_r[m][r] + xres[idx];
                }
    }
}

// ---------------- depthwise 3x3 + bias -> bf16 y2
__global__ __launch_bounds__(256) void k_dw(const u16* __restrict__ y1,
                                            const float* __restrict__ wdw,
                                            const float* __restrict__ bdw,
                                            u16* __restrict__ y2)
{
    const int b  = blockIdx.z;
    const int ch = blockIdx.y;
    const int p  = (blockIdx.x * 256 + (int)threadIdx.x) * 8;
    const int row = p >> 7;
    const int col = p & 127;
    const size_t ib = ((size_t)b * DIM3 + ch) * PP;
    const u16* img = y1 + ib;

    float w9[9];
#pragma unroll
    for (int i = 0; i < 9; ++i) w9[i] = wdw[ch * 9 + i];
    const float bv = bdw[ch];

    float vr[3][10];
#pragma unroll
    for (int dy = 0; dy < 3; ++dy) {
        const int r = row + dy - 1;
        if (r >= 0 && r < HH) {
            const u16* rp = img + r * WW2 + col;
            union { int4 v; u16 u[8]; } cc;
            cc.v = *reinterpret_cast<const int4*>(rp);
#pragma unroll
            for (int j = 0; j < 8; ++j) vr[dy][j + 1] = bf2f(cc.u[j]);
            vr[dy][0] = (col > 0) ? bf2f(rp[-1]) : 0.f;
            vr[dy][9] = (col + 8 < WW2) ? bf2f(rp[8]) : 0.f;
        } else {
#pragma unroll
            for (int j = 0; j < 10; ++j) vr[dy][j] = 0.f;
        }
    }
    union { int4 v; u16 u[8]; } ou;
#pragma unroll
    for (int j = 0; j < 8; ++j) {
        float a = bv;
#pragma unroll
        for (int dy = 0; dy < 3; ++dy)
#pragma unroll
            for (int dx = 0; dx < 3; ++dx)
                a = fmaf(w9[dy * 3 + dx], vr[dy][j + dx], a);
        ou.u[j] = f2bf(a);
    }
    *reinterpret_cast<int4*>(y2 + ib + p) = ou.v;
}

// ---------------- Gram-matrix partials (q.k, q.q, k.k) per batch
__global__ __launch_bounds__(256) void k_dots(const u16* __restrict__ y2,
                                              float* __restrict__ partial)
{
    const int b  = blockIdx.z;
    const int cy = blockIdx.y;
    const int c0 = cy * 24;
    const int p2 = (blockIdx.x * 256 + (int)threadIdx.x) * 2;
    const u16* qb = y2 + (size_t)b * DIM3 * PP + p2;
    const u16* kb = qb + (size_t)DIM * PP;

    float qk[64], qq[8], ks[8];
#pragma unroll
    for (int i = 0; i < 64; ++i) qk[i] = 0.f;
#pragma unroll
    for (int i = 0; i < 8; ++i) { qq[i] = 0.f; ks[i] = 0.f; }

    for (int c = c0; c < c0 + 24; ++c) {
        float q0[8], q1[8], k0[8], k1[8];
#pragma unroll
        for (int n = 0; n < 8; ++n) {
            const unsigned int qv = *reinterpret_cast<const unsigned int*>(qb + (size_t)(n * CPG + c) * PP);
            q0[n] = __uint_as_float(qv << 16);
            q1[n] = __uint_as_float(qv & 0xffff0000u);
            const unsigned int kv = *reinterpret_cast<const unsigned int*>(kb + (size_t)(n * CPG + c) * PP);
            k0[n] = __uint_as_float(kv << 16);
            k1[n] = __uint_as_float(kv & 0xffff0000u);
        }
#pragma unroll
        for (int n = 0; n < 8; ++n) {
#pragma unroll
            for (int m = 0; m < 8; ++m)
                qk[n * 8 + m] += q0[n] * k0[m] + q1[n] * k1[m];
            qq[n] += q0[n] * q0[n] + q1[n] * q1[n];
            ks[n] += k0[n] * k0[n] + k1[n] * k1[n];
        }
    }
    const int wave = (int)threadIdx.x >> 6;
    const int lane = (int)threadIdx.x & 63;
    const size_t rowidx = (size_t)((((b * 2 + cy) * 32 + blockIdx.x) * 4 + wave)) * 80;
#pragma unroll
    for (int i = 0; i < 80; ++i) {
        float v = (i < 64) ? qk[i] : ((i < 72) ? qq[i - 64] : ks[i - 72]);
        v += __shfl_down(v, 32);
        v += __shfl_down(v, 16);
        v += __shfl_down(v, 8);
        v += __shfl_down(v, 4);
        v += __shfl_down(v, 2);
        v += __shfl_down(v, 1);
        if (lane == 0) partial[rowidx + i] = v;
    }
}

// ---------------- reduce partials, normalize, softmax -> attn[b][8][8]
__global__ __launch_bounds__(128) void k_attn(const float* __restrict__ partial,
                                              const float* __restrict__ temp,
                                              float* __restrict__ attn)
{
    const int b = blockIdx.x;
    const int t = threadIdx.x;
    __shared__ float dots[80];
    __shared__ float sc[8][8];
    if (t < 80) {
        float s = 0.f;
        for (int i = 0; i < 256; ++i)
            s += partial[((size_t)b * 256 + i) * 80 + t];
        dots[t] = s;
    }
    __syncthreads();
    if (t < 64) {
        const int n = t >> 3, m = t & 7;
        const float qn = fmaxf(sqrtf(dots[64 + n]), 1e-12f);
        const float km = fmaxf(sqrtf(dots[72 + m]), 1e-12f);
        sc[n][m] = dots[n * 8 + m] / (qn * km) * temp[0];
    }
    __syncthreads();
    if (t < 8) {
        float mx = -3.0e38f;
#pragma unroll
        for (int m = 0; m < 8; ++m) mx = fmaxf(mx, sc[t][m]);
        float e[8], s = 0.f;
#pragma unroll
        for (int m = 0; m < 8; ++m) { e[m] = expf(sc[t][m] - mx); s += e[m]; }
        const float inv = 1.f / s;
#pragma unroll
        for (int m = 0; m < 8; ++m) attn[(b * 8 + t) * 8 + m] = e[m] * inv;
    }
}

// ---------------- Weff[b][co][m*48+c] = sum_n wproj[co][n*48+c]*attn[n][m]  (bf16 out)
__global__ __launch_bounds__(128) void k_weff(const float* __restrict__ attn,
                                              const float* __restrict__ wproj,
                                              u16* __restrict__ weff)
{
    const int b  = blockIdx.y;
    const int co = blockIdx.x;
    const int t  = threadIdx.x;
    __shared__ float a[64];
    if (t < 64) a[t] = attn[b * 64 + t];
    __syncthreads();
    const float* wrow = wproj + (size_t)co * DIM;
    u16* wout = weff + ((size_t)b * DIM + co) * DIM;
    for (int i = t; i < DIM; i += 128) {
        const int m = i / CPG;
        const int c = i - m * CPG;
        float s = 0.f;
#pragma unroll
        for (int n = 0; n < 8; ++n) s += wrow[n * CPG + c] * a[n * 8 + m];
        wout[i] = f2bf(s);
    }
}

extern "C" void kernel_launch(void* const* d_in, const int* in_sizes, int n_in,
                              void* d_out, int out_size, void* d_ws, size_t ws_size,
                              hipStream_t stream)
{
    const float* x      = (const float*)d_in[0];
    const float* temp   = (const float*)d_in[1];
    const float* w_qkv  = (const float*)d_in[2];
    const float* b_qkv  = (const float*)d_in[3];
    const float* w_dw   = (const float*)d_in[4];
    const float* b_dw   = (const float*)d_in[5];
    const float* w_proj = (const float*)d_in[6];
    const float* b_proj = (const float*)d_in[7];
    float* out = (float*)d_out;

    char* ws = (char*)d_ws;
    const size_t SZ_QKV = (size_t)BB * DIM3 * PP * sizeof(u16);  // 150,994,944
    const size_t SZ_XT  = (size_t)BB * PP * DIM * sizeof(u16);   //  50,331,648

    // region 0: [0, SZ_QKV)
    u16* y1 = (u16*)ws;                           // k_gemm<0> -> k_dw, then dead
    float* partial = (float*)ws;                  // 327,680 B (after k_dw)
    float* attn    = (float*)(ws + 327680);       // 1,024 B
    u16*   weffb   = (u16*)(ws + 331776);         // 1,179,648 B (ends 1,511,424)
    u16*   vt      = (u16*)(ws + 2097152);        // 50,331,648 B (ends ~52.4 MB)

    // region 1: [SZ_QKV, SZ_QKV + SZ_QKV)
    u16* y2  = (u16*)(ws + SZ_QKV);               // k_dw onward
    u16* xt  = (u16*)(ws + SZ_QKV);               // pre-k_dw only (aliased, dead before y2 write)
    u16* wbf = (u16*)(ws + SZ_QKV + SZ_XT);       // 884,736 B (pre-k_dw only)

    k_wcvt<<<dim3(DIM3 * DIM / 1024), 256, 0, stream>>>(w_qkv, wbf);
    k_tr_x<<<dim3(PP / 64, DIM / 64, BB), 256, 0, stream>>>(x, xt);
    k_gemm<0><<<dim3(PP / 128, DIM3 / 128, BB), 256, 0, stream>>>(
        wbf, 0, xt, b_qkv, y1, nullptr, nullptr);
    k_dw<<<dim3(PP / 2048, DIM3, BB), 256, 0, stream>>>(y1, w_dw, b_dw, y2);
    k_dots<<<dim3(32, 2, BB), 256, 0, stream>>>(y2, partial);
    k_attn<<<dim3(BB), 128, 0, stream>>>(partial, temp, attn);
    k_weff<<<dim3(DIM, BB), 128, 0, stream>>>(attn, w_proj, weffb);
    k_tr_v<<<dim3(PP / 64, DIM / 64, BB), 256, 0, stream>>>(y2, vt);
    k_gemm<1><<<dim3(PP / 128, DIM / 128, BB), 256, 0, stream>>>(
        weffb, DIM * DIM, vt, b_proj, nullptr, x, out);
}

// Round 7
// 664.141 us; speedup vs baseline: 1.7948x; 1.1161x over previous
//
#include <hip/hip_runtime.h>
#include <hip/hip_bf16.h>

#define BB 4
#define CPG 48
#define HH 128
#define WW2 128
#define PP 16384
#define DIM 384
#define DIM3 1152

typedef unsigned short u16;
typedef __attribute__((ext_vector_type(8))) short bf16x8;
typedef __attribute__((ext_vector_type(4))) float f32x4;

__device__ __forceinline__ float bf2f(u16 u) {
    return __uint_as_float(((unsigned int)u) << 16);
}
__device__ __forceinline__ u16 f2bf(float f) {
    unsigned int u = __float_as_uint(f);
    unsigned int r = (u + 0x7fffu + ((u >> 16) & 1u)) >> 16;
    return (u16)r;
}

// LDS swizzle: rows are 128B; XOR the 16B-slot index with (row&7) to spread banks
__device__ __forceinline__ int swz(int row, int kb) {
    return row * 128 + (kb ^ ((row & 7) << 4));
}

// ---------------- convert w_qkv fp32 -> bf16
__global__ __launch_bounds__(256) void k_wcvt(const float* __restrict__ w,
                                              u16* __restrict__ wbf)
{
    const int i4 = (blockIdx.x * 256 + threadIdx.x) * 4;
    float4 v = *reinterpret_cast<const float4*>(w + i4);
    ushort4 s;
    s.x = f2bf(v.x); s.y = f2bf(v.y); s.z = f2bf(v.z); s.w = f2bf(v.w);
    *reinterpret_cast<ushort4*>(wbf + i4) = s;
}

// ---------------- transpose x [b][k=384][p] fp32 -> Xt [b][p][k=384] bf16
__global__ __launch_bounds__(256) void k_tr_x(const float* __restrict__ x,
                                              u16* __restrict__ xt)
{
    const int b = blockIdx.z;
    const int k0 = blockIdx.y * 64;
    const int p0 = blockIdx.x * 64;
    const int t = threadIdx.x;
    __shared__ u16 T[64][68];

    const int kl = t >> 4;          // 0..15
    const int pl = (t & 15) * 4;    // 0..60
#pragma unroll
    for (int ks = 0; ks < 4; ++ks) {
        const int k = ks * 16 + kl;
        float4 v = *reinterpret_cast<const float4*>(&x[((size_t)b * DIM + k0 + k) * PP + p0 + pl]);
        ushort4 s;
        s.x = f2bf(v.x); s.y = f2bf(v.y); s.z = f2bf(v.z); s.w = f2bf(v.w);
        *reinterpret_cast<ushort4*>(&T[k][pl]) = s;
    }
    __syncthreads();
    const int pr = t >> 2;          // 0..63
    const int kg = (t & 3) * 16;    // 0,16,32,48
    __align__(16) u16 tmp[16];
#pragma unroll
    for (int j = 0; j < 16; ++j) tmp[j] = T[kg + j][pr];
    u16* dst = xt + ((size_t)b * PP + p0 + pr) * DIM + k0 + kg;
    *reinterpret_cast<uint4*>(dst)     = *reinterpret_cast<uint4*>(tmp);
    *reinterpret_cast<uint4*>(dst + 8) = *reinterpret_cast<uint4*>(tmp + 8);
}

// ---------------- transpose v part of y2 [b][768+c][p] bf16 -> Vt [b][p][c=384] bf16
__global__ __launch_bounds__(256) void k_tr_v(const u16* __restrict__ y2,
                                              u16* __restrict__ vt)
{
    const int b = blockIdx.z;
    const int c0 = blockIdx.y * 64;
    const int p0 = blockIdx.x * 64;
    const int t = threadIdx.x;
    __shared__ u16 T[64][68];

    const int cl = t >> 4;
    const int pl = (t & 15) * 4;
#pragma unroll
    for (int cs = 0; cs < 4; ++cs) {
        const int c = cs * 16 + cl;
        ushort4 v = *reinterpret_cast<const ushort4*>(
            &y2[((size_t)b * DIM3 + 2 * DIM + c0 + c) * PP + p0 + pl]);
        *reinterpret_cast<ushort4*>(&T[c][pl]) = v;
    }
    __syncthreads();
    const int pr = t >> 2;
    const int kg = (t & 3) * 16;
    __align__(16) u16 tmp[16];
#pragma unroll
    for (int j = 0; j < 16; ++j) tmp[j] = T[kg + j][pr];
    u16* dst = vt + ((size_t)b * PP + p0 + pr) * DIM + c0 + kg;
    *reinterpret_cast<uint4*>(dst)     = *reinterpret_cast<uint4*>(tmp);
    *reinterpret_cast<uint4*>(dst + 8) = *reinterpret_cast<uint4*>(tmp + 8);
}

// ---------------- MFMA GEMM: C[b][co][p] = sum_k A[(b)][co][k] * Bt[b][p][k]
// MODE 0: += bias, write bf16 ybf.  MODE 1: += bias + xres, write fp32 fout.
template<int MODE>
__global__ __launch_bounds__(256) void k_gemm(const u16* __restrict__ A, int aStride,
                                              const u16* __restrict__ Bt,
                                              const float* __restrict__ bias,
                                              u16* __restrict__ ybf,
                                              const float* __restrict__ xres,
                                              float* __restrict__ fout)
{
    const int b   = blockIdx.z;
    const int co0 = blockIdx.y * 128;
    const int p0  = blockIdx.x * 128;
    const int t   = threadIdx.x;
    const int l   = t & 63;
    const int wid = t >> 6;
    const int wr  = wid >> 1;      // 0..1 -> row half
    const int wc  = wid & 1;       // 0..1 -> col half
    const int lr  = l & 15;
    const int lg  = l >> 4;        // 0..3

    __shared__ __align__(16) char lds[32768];
    char* AsB = lds;               // [128 rows][64 k] bf16, swizzled
    char* BsB = lds + 16384;

    f32x4 acc[4][4];
#pragma unroll
    for (int m = 0; m < 4; ++m)
#pragma unroll
        for (int n = 0; n < 4; ++n) acc[m][n] = (f32x4){0.f, 0.f, 0.f, 0.f};

    const u16* Ab  = A  + (size_t)b * aStride;
    const u16* Btb = Bt + (size_t)b * PP * DIM;

    const int srow = t >> 1;       // 0..127
    const int shalf = t & 1;       // 0..1 (32 bf16 = 64B)

    for (int k0 = 0; k0 < DIM; k0 += 64) {
        const u16* sa = Ab  + (size_t)(co0 + srow) * DIM + k0 + shalf * 32;
        const u16* sb = Btb + (size_t)(p0  + srow) * DIM + k0 + shalf * 32;
        uint4 ra[2], rb[2];
#pragma unroll
        for (int i = 0; i < 2; ++i) {
            ra[i] = *reinterpret_cast<const uint4*>(sa + i * 8);
            rb[i] = *reinterpret_cast<const uint4*>(sb + i * 8);
        }
        uint4 ra2[2], rb2[2];
#pragma unroll
        for (int i = 0; i < 2; ++i) {
            ra2[i] = *reinterpret_cast<const uint4*>(sa + 16 + i * 8);
            rb2[i] = *reinterpret_cast<const uint4*>(sb + 16 + i * 8);
        }
        if (k0) __syncthreads();
#pragma unroll
        for (int i = 0; i < 2; ++i) {
            const int kb = shalf * 64 + i * 16;
            *reinterpret_cast<uint4*>(AsB + swz(srow, kb)) = ra[i];
            *reinterpret_cast<uint4*>(BsB + swz(srow, kb)) = rb[i];
        }
#pragma unroll
        for (int i = 0; i < 2; ++i) {
            const int kb = shalf * 64 + 32 + i * 16;
            *reinterpret_cast<uint4*>(AsB + swz(srow, kb)) = ra2[i];
            *reinterpret_cast<uint4*>(BsB + swz(srow, kb)) = rb2[i];
        }
        __syncthreads();

#pragma unroll
        for (int kk = 0; kk < 64; kk += 32) {
            const int kbyte = kk * 2 + lg * 16;
            bf16x8 av[4], bv[4];
#pragma unroll
            for (int m = 0; m < 4; ++m) {
                const int row = wr * 64 + m * 16 + lr;
                av[m] = *reinterpret_cast<const bf16x8*>(AsB + swz(row, kbyte));
            }
#pragma unroll
            for (int n = 0; n < 4; ++n) {
                const int row = wc * 64 + n * 16 + lr;
                bv[n] = *reinterpret_cast<const bf16x8*>(BsB + swz(row, kbyte));
            }
#pragma unroll
            for (int m = 0; m < 4; ++m)
#pragma unroll
                for (int n = 0; n < 4; ++n)
                    acc[m][n] = __builtin_amdgcn_mfma_f32_16x16x32_bf16(
                        av[m], bv[n], acc[m][n], 0, 0, 0);
        }
    }

    // bias per (m, r): row = wr*64 + m*16 + lg*4 + r
    float bias_r[4][4];
#pragma unroll
    for (int m = 0; m < 4; ++m)
#pragma unroll
        for (int r = 0; r < 4; ++r)
            bias_r[m][r] = bias[co0 + wr * 64 + m * 16 + lg * 4 + r];

    if (MODE == 0) {
        __syncthreads();
        u16* Cs = reinterpret_cast<u16*>(lds);
#pragma unroll
        for (int m = 0; m < 4; ++m)
#pragma unroll
            for (int n = 0; n < 4; ++n)
#pragma unroll
                for (int r = 0; r < 4; ++r) {
                    const int row = wr * 64 + m * 16 + lg * 4 + r;
                    const int col = wc * 64 + n * 16 + lr;
                    Cs[row * 128 + col] = f2bf(acc[m][n][r] + bias_r[m][r]);
                }
        __syncthreads();
        // coalesced store: 16 lanes cover one 256B row segment; a wave writes
        // 4 full rows per instruction (1 KB contiguous groups)
        const int rr = t >> 4;          // 0..15
        const int cs = (t & 15) * 8;    // u16 col
#pragma unroll
        for (int j = 0; j < 8; ++j) {
            const int row = j * 16 + rr;
            *reinterpret_cast<uint4*>(&ybf[((size_t)b * DIM3 + co0 + row) * PP + p0 + cs]) =
                *reinterpret_cast<const uint4*>(&Cs[row * 128 + cs]);
        }
    } else {
        // fp32 epilogue via LDS in two 64-row half-passes; rows 0-63 owned by
        // waves wr==0, rows 64-127 by wr==1. [64][128] fp32 = 32768 B.
        float* Cf = reinterpret_cast<float*>(lds);
#pragma unroll
        for (int h = 0; h < 2; ++h) {
            __syncthreads();
            if (wr == h) {
#pragma unroll
                for (int m = 0; m < 4; ++m)
#pragma unroll
                    for (int n = 0; n < 4; ++n)
#pragma unroll
                        for (int r = 0; r < 4; ++r) {
                            const int lrow = m * 16 + lg * 4 + r;
                            const int col = wc * 64 + n * 16 + lr;
                            Cf[lrow * 128 + col] = acc[m][n][r] + bias_r[m][r];
                        }
            }
            __syncthreads();
            // 32 lanes cover one 512B fp32 row; 8 rows per round, 8 rounds
            const int rr = t >> 5;          // 0..7
            const int cc = (t & 31) * 4;    // fp32 col
#pragma unroll
            for (int j = 0; j < 8; ++j) {
                const int lrow = j * 8 + rr;
                const int grow = h * 64 + lrow;
                const size_t idx = ((size_t)b * DIM + co0 + grow) * PP + p0 + cc;
                float4 xr = *reinterpret_cast<const float4*>(&xres[idx]);
                float4 cv = *reinterpret_cast<const float4*>(&Cf[lrow * 128 + cc]);
                cv.x += xr.x; cv.y += xr.y; cv.z += xr.z; cv.w += xr.w;
                *reinterpret_cast<float4*>(&fout[idx]) = cv;
            }
        }
    }
}

// ---------------- depthwise 3x3 + bias -> bf16 y2
__global__ __launch_bounds__(256) void k_dw(const u16* __restrict__ y1,
                                            const float* __restrict__ wdw,
                                            const float* __restrict__ bdw,
                                            u16* __restrict__ y2)
{
    const int b  = blockIdx.z;
    const int ch = blockIdx.y;
    const int p  = (blockIdx.x * 256 + (int)threadIdx.x) * 8;
    const int row = p >> 7;
    const int col = p & 127;
    const size_t ib = ((size_t)b * DIM3 + ch) * PP;
    const u16* img = y1 + ib;

    float w9[9];
#pragma unroll
    for (int i = 0; i < 9; ++i) w9[i] = wdw[ch * 9 + i];
    const float bv = bdw[ch];

    float vr[3][10];
#pragma unroll
    for (int dy = 0; dy < 3; ++dy) {
        const int r = row + dy - 1;
        if (r >= 0 && r < HH) {
            const u16* rp = img + r * WW2 + col;
            union { int4 v; u16 u[8]; } cc;
            cc.v = *reinterpret_cast<const int4*>(rp);
#pragma unroll
            for (int j = 0; j < 8; ++j) vr[dy][j + 1] = bf2f(cc.u[j]);
            vr[dy][0] = (col > 0) ? bf2f(rp[-1]) : 0.f;
            vr[dy][9] = (col + 8 < WW2) ? bf2f(rp[8]) : 0.f;
        } else {
#pragma unroll
            for (int j = 0; j < 10; ++j) vr[dy][j] = 0.f;
        }
    }
    union { int4 v; u16 u[8]; } ou;
#pragma unroll
    for (int j = 0; j < 8; ++j) {
        float a = bv;
#pragma unroll
        for (int dy = 0; dy < 3; ++dy)
#pragma unroll
            for (int dx = 0; dx < 3; ++dx)
                a = fmaf(w9[dy * 3 + dx], vr[dy][j + dx], a);
        ou.u[j] = f2bf(a);
    }
    *reinterpret_cast<int4*>(y2 + ib + p) = ou.v;
}

// ---------------- Gram-matrix partials (q.k, q.q, k.k) per batch
__global__ __launch_bounds__(256) void k_dots(const u16* __restrict__ y2,
                                              float* __restrict__ partial)
{
    const int b  = blockIdx.z;
    const int cy = blockIdx.y;
    const int c0 = cy * 24;
    const int p2 = (blockIdx.x * 256 + (int)threadIdx.x) * 2;
    const u16* qb = y2 + (size_t)b * DIM3 * PP + p2;
    const u16* kb = qb + (size_t)DIM * PP;

    float qk[64], qq[8], ks[8];
#pragma unroll
    for (int i = 0; i < 64; ++i) qk[i] = 0.f;
#pragma unroll
    for (int i = 0; i < 8; ++i) { qq[i] = 0.f; ks[i] = 0.f; }

    for (int c = c0; c < c0 + 24; ++c) {
        float q0[8], q1[8], k0[8], k1[8];
#pragma unroll
        for (int n = 0; n < 8; ++n) {
            const unsigned int qv = *reinterpret_cast<const unsigned int*>(qb + (size_t)(n * CPG + c) * PP);
            q0[n] = __uint_as_float(qv << 16);
            q1[n] = __uint_as_float(qv & 0xffff0000u);
            const unsigned int kv = *reinterpret_cast<const unsigned int*>(kb + (size_t)(n * CPG + c) * PP);
            k0[n] = __uint_as_float(kv << 16);
            k1[n] = __uint_as_float(kv & 0xffff0000u);
        }
#pragma unroll
        for (int n = 0; n < 8; ++n) {
#pragma unroll
            for (int m = 0; m < 8; ++m)
                qk[n * 8 + m] += q0[n] * k0[m] + q1[n] * k1[m];
            qq[n] += q0[n] * q0[n] + q1[n] * q1[n];
            ks[n] += k0[n] * k0[n] + k1[n] * k1[n];
        }
    }
    const int wave = (int)threadIdx.x >> 6;
    const int lane = (int)threadIdx.x & 63;
    const size_t rowidx = (size_t)((((b * 2 + cy) * 32 + blockIdx.x) * 4 + wave)) * 80;
#pragma unroll
    for (int i = 0; i < 80; ++i) {
        float v = (i < 64) ? qk[i] : ((i < 72) ? qq[i - 64] : ks[i - 72]);
        v += __shfl_down(v, 32);
        v += __shfl_down(v, 16);
        v += __shfl_down(v, 8);
        v += __shfl_down(v, 4);
        v += __shfl_down(v, 2);
        v += __shfl_down(v, 1);
        if (lane == 0) partial[rowidx + i] = v;
    }
}

// ---------------- reduce partials, normalize, softmax -> attn[b][8][8]
__global__ __launch_bounds__(128) void k_attn(const float* __restrict__ partial,
                                              const float* __restrict__ temp,
                                              float* __restrict__ attn)
{
    const int b = blockIdx.x;
    const int t = threadIdx.x;
    __shared__ float dots[80];
    __shared__ float sc[8][8];
    if (t < 80) {
        float s = 0.f;
        for (int i = 0; i < 256; ++i)
            s += partial[((size_t)b * 256 + i) * 80 + t];
        dots[t] = s;
    }
    __syncthreads();
    if (t < 64) {
        const int n = t >> 3, m = t & 7;
        const float qn = fmaxf(sqrtf(dots[64 + n]), 1e-12f);
        const float km = fmaxf(sqrtf(dots[72 + m]), 1e-12f);
        sc[n][m] = dots[n * 8 + m] / (qn * km) * temp[0];
    }
    __syncthreads();
    if (t < 8) {
        float mx = -3.0e38f;
#pragma unroll
        for (int m = 0; m < 8; ++m) mx = fmaxf(mx, sc[t][m]);
        float e[8], s = 0.f;
#pragma unroll
        for (int m = 0; m < 8; ++m) { e[m] = expf(sc[t][m] - mx); s += e[m]; }
        const float inv = 1.f / s;
#pragma unroll
        for (int m = 0; m < 8; ++m) attn[(b * 8 + t) * 8 + m] = e[m] * inv;
    }
}

// ---------------- Weff[b][co][m*48+c] = sum_n wproj[co][n*48+c]*attn[n][m]  (bf16 out)
__global__ __launch_bounds__(128) void k_weff(const float* __restrict__ attn,
                                              const float* __restrict__ wproj,
                                              u16* __restrict__ weff)
{
    const int b  = blockIdx.y;
    const int co = blockIdx.x;
    const int t  = threadIdx.x;
    __shared__ float a[64];
    if (t < 64) a[t] = attn[b * 64 + t];
    __syncthreads();
    const float* wrow = wproj + (size_t)co * DIM;
    u16* wout = weff + ((size_t)b * DIM + co) * DIM;
    for (int i = t; i < DIM; i += 128) {
        const int m = i / CPG;
        const int c = i - m * CPG;
        float s = 0.f;
#pragma unroll
        for (int n = 0; n < 8; ++n) s += wrow[n * CPG + c] * a[n * 8 + m];
        wout[i] = f2bf(s);
    }
}

extern "C" void kernel_launch(void* const* d_in, const int* in_sizes, int n_in,
                              void* d_out, int out_size, void* d_ws, size_t ws_size,
                              hipStream_t stream)
{
    const float* x      = (const float*)d_in[0];
    const float* temp   = (const float*)d_in[1];
    const float* w_qkv  = (const float*)d_in[2];
    const float* b_qkv  = (const float*)d_in[3];
    const float* w_dw   = (const float*)d_in[4];
    const float* b_dw   = (const float*)d_in[5];
    const float* w_proj = (const float*)d_in[6];
    const float* b_proj = (const float*)d_in[7];
    float* out = (float*)d_out;

    char* ws = (char*)d_ws;
    const size_t SZ_QKV = (size_t)BB * DIM3 * PP * sizeof(u16);  // 150,994,944
    const size_t SZ_XT  = (size_t)BB * PP * DIM * sizeof(u16);   //  50,331,648

    // region 0: [0, SZ_QKV)
    u16* y1 = (u16*)ws;                           // k_gemm<0> -> k_dw, then dead
    float* partial = (float*)ws;                  // 327,680 B (after k_dw)
    float* attn    = (float*)(ws + 327680);       // 1,024 B
    u16*   weffb   = (u16*)(ws + 331776);         // 1,179,648 B (ends 1,511,424)
    u16*   vt      = (u16*)(ws + 2097152);        // 50,331,648 B (ends ~52.4 MB)

    // region 1: [SZ_QKV, SZ_QKV + SZ_QKV)
    u16* y2  = (u16*)(ws + SZ_QKV);               // k_dw onward
    u16* xt  = (u16*)(ws + SZ_QKV);               // pre-k_dw only (aliased, dead before y2 write)
    u16* wbf = (u16*)(ws + SZ_QKV + SZ_XT);       // 884,736 B (pre-k_dw only)

    k_wcvt<<<dim3(DIM3 * DIM / 1024), 256, 0, stream>>>(w_qkv, wbf);
    k_tr_x<<<dim3(PP / 64, DIM / 64, BB), 256, 0, stream>>>(x, xt);
    k_gemm<0><<<dim3(PP / 128, DIM3 / 128, BB), 256, 0, stream>>>(
        wbf, 0, xt, b_qkv, y1, nullptr, nullptr);
    k_dw<<<dim3(PP / 2048, DIM3, BB), 256, 0, stream>>>(y1, w_dw, b_dw, y2);
    k_dots<<<dim3(32, 2, BB), 256, 0, stream>>>(y2, partial);
    k_attn<<<dim3(BB), 128, 0, stream>>>(partial, temp, attn);
    k_weff<<<dim3(DIM, BB), 128, 0, stream>>>(attn, w_proj, weffb);
    k_tr_v<<<dim3(PP / 64, DIM / 64, BB), 256, 0, stream>>>(y2, vt);
    k_gemm<1><<<dim3(PP / 128, DIM / 128, BB), 256, 0, stream>>>(
        weffb, DIM * DIM, vt, b_proj, nullptr, x, out);
}